// Round 5
// baseline (421.606 us; speedup 1.0000x reference)
//
#include <hip/hip_runtime.h>

#define DEVI __device__ __forceinline__

typedef float f32x4 __attribute__((ext_vector_type(4)));
typedef __bf16 bf16x8 __attribute__((ext_vector_type(8)));

constexpr int S   = 2048;
constexpr int HID = 1024;
constexpr int HD  = 64;
constexpr int O3  = 3072;
constexpr int KF  = 9216;   // 1024 silu + 1024*8 spline

DEVI unsigned short f2bf(float f) {
  unsigned int u = __float_as_uint(f);
  u = (u + 0x7FFFu + ((u >> 16) & 1u)) >> 16;
  return (unsigned short)u;
}
DEVI float b2f(unsigned int u) { return __uint_as_float(u << 16); }
DEVI float fexp(float x) { return __builtin_amdgcn_exp2f(x * 1.44269504089f); }

DEVI void gload16(const void* g, void* l) {
  __builtin_amdgcn_global_load_lds((const __attribute__((address_space(1))) void*)g,
                                   (__attribute__((address_space(3))) void*)l, 16, 0, 0);
}

#define BAR() asm volatile("s_barrier" ::: "memory")
#define VMC0() asm volatile("s_waitcnt vmcnt(0)" ::: "memory")
#define VMC2() asm volatile("s_waitcnt vmcnt(2)" ::: "memory")

// ---- build bf16 combined weight Wc[3072][9216] = [base | spline*scaler] ----
__global__ __launch_bounds__(256) void kconv_w(const float* __restrict__ bw,
    const float* __restrict__ sw, const float* __restrict__ sc,
    unsigned short* __restrict__ Wc) {
  unsigned int t = blockIdx.x * 256 + threadIdx.x;    // < 3072*1152
  unsigned int o = t / 1152, jc = t % 1152;
  unsigned int j = jc * 8;
  float v[8];
  if (j < 1024) {
    const float4* p = (const float4*)(bw + (size_t)o * 1024 + j);
    float4 a = p[0], b = p[1];
    v[0]=a.x; v[1]=a.y; v[2]=a.z; v[3]=a.w; v[4]=b.x; v[5]=b.y; v[6]=b.z; v[7]=b.w;
  } else {
    unsigned int i = (j - 1024) >> 3;
    float s = sc[(size_t)o * 1024 + i];
    const float4* p = (const float4*)(sw + ((size_t)o * 1024 + i) * 8);
    float4 a = p[0], b = p[1];
    v[0]=a.x*s; v[1]=a.y*s; v[2]=a.z*s; v[3]=a.w*s; v[4]=b.x*s; v[5]=b.y*s; v[6]=b.z*s; v[7]=b.w*s;
  }
  union { unsigned short u[8]; uint4 q; } pk;
  #pragma unroll
  for (int c = 0; c < 8; ++c) pk.u[c] = f2bf(v[c]);
  *(uint4*)(Wc + (size_t)o * KF + j) = pk.q;
}

__global__ __launch_bounds__(256) void kconv_outw(const float* __restrict__ ow,
    unsigned short* __restrict__ Wo) {
  unsigned int t = blockIdx.x * 256 + threadIdx.x;    // < 131072
  unsigned int o = t >> 7, j = (t & 127) * 8;
  const float4* p = (const float4*)(ow + (size_t)o * 1024 + j);
  float4 a = p[0], b = p[1];
  float v[8] = {a.x, a.y, a.z, a.w, b.x, b.y, b.z, b.w};
  union { unsigned short u[8]; uint4 q; } pk;
  #pragma unroll
  for (int c = 0; c < 8; ++c) pk.u[c] = f2bf(v[c]);
  *(uint4*)(Wo + (size_t)o * 1024 + j) = pk.q;
}

// ---- features F[2048][9216] bf16 : [silu(x) | b_splines(x)] ----
__global__ __launch_bounds__(256) void kfeatures(const float* __restrict__ x,
    const float* __restrict__ grid, unsigned short* __restrict__ F) {
  unsigned int t = blockIdx.x * 256 + threadIdx.x;    // < 2048*1024
  unsigned int n = t >> 10, i = t & 1023;
  float xv = x[t];
  float sil = xv / (1.f + expf(-xv));
  F[(size_t)n * KF + i] = f2bf(sil);
  float g[12];
  #pragma unroll
  for (int j = 0; j < 12; ++j) g[j] = grid[j];        // wave-uniform row 0
  float b[11];
  #pragma unroll
  for (int j = 0; j < 11; ++j) b[j] = (xv >= g[j] && xv < g[j + 1]) ? 1.f : 0.f;
  #pragma unroll
  for (int ord = 1; ord <= 3; ++ord) {
    float inv[11];
    #pragma unroll
    for (int a = 0; a + ord < 12 && a < 11; ++a) {
      float d = g[a + ord] - g[a];
      float r = __builtin_amdgcn_rcpf(d);
      inv[a] = r * (2.f - d * r);                     // one Newton step
    }
    #pragma unroll
    for (int j = 0; j + ord < 11; ++j)
      b[j] = (xv - g[j]) * inv[j] * b[j]
           + (g[j + ord + 1] - xv) * inv[j + 1] * b[j + 1];
  }
  union { unsigned short u[8]; uint4 q; } pk;
  #pragma unroll
  for (int c = 0; c < 8; ++c) pk.u[c] = f2bf(b[c]);
  *(uint4*)(F + (size_t)n * KF + 1024 + i * 8) = pk.q;
}

// ---- 8-phase 256x192 bf16 GEMM (T2+T3+T4+T5): qkv partials, split-K=2 ----
// grid (8,16,2) = 256 blocks = 1/CU.  512 threads, 8 waves (2Mx4N),
// per-wave 128x48 out.  LDS 112KB: A dbuf 2x[2 halves][128][64],
// B dbuf 2x[192][64].  Raw s_barrier (no vmcnt drain); vmcnt(2) at ph4/ph8.
__global__ __launch_bounds__(512) void kgemm256(const unsigned short* __restrict__ A,
    const unsigned short* __restrict__ W, unsigned short* __restrict__ C) {
  int lin = blockIdx.x + (blockIdx.y << 3) + (blockIdx.z << 7);
  int swz = (lin & 7) * 32 + (lin >> 3);              // bijective XCD swizzle
  int kz = swz >> 7;
  int r = swz & 127;
  int bm = r >> 4, bn = r & 15;
  const int tid = threadIdx.x;
  const int wid = tid >> 6;
  const int lane = tid & 63;
  const int l16 = lane & 15, g4 = lane >> 4;
  const int wr = wid >> 2, wc = wid & 3;
  const int koff = kz * 72;                           // K-tiles of 64

  __shared__ __align__(16) unsigned short As[2][2][128 * 64];
  __shared__ __align__(16) unsigned short Bs[2][192 * 64];

  const size_t rA0 = (size_t)bm * 256;
  const size_t rB0 = (size_t)bn * 192;

  auto stageA = [&](int buf, int half, int t) {       // 128x64 half-tile, 2 loads
    const unsigned short* src = A + (rA0 + half * 128) * (size_t)KF + (size_t)(koff + t) * 64;
    char* lds = (char*)As[buf][half];
    #pragma unroll
    for (int rr = 0; rr < 2; ++rr) {
      int chunk = rr * 512 + tid;
      int row = chunk >> 3;
      int c8 = (chunk & 7) ^ (row & 7);               // pre-swizzled source
      gload16(src + (size_t)row * KF + c8 * 8, lds + (rr * 512 + wid * 64) * 16);
    }
  };
  auto stageB = [&](int buf, int third, int t) {      // 64x64 third, 1 load
    const unsigned short* src = W + (rB0 + third * 64) * (size_t)KF + (size_t)(koff + t) * 64;
    char* lds = (char*)Bs[buf] + third * 8192;
    int row = tid >> 3;
    int c8 = (tid & 7) ^ (row & 7);
    gload16(src + (size_t)row * KF + c8 * 8, lds + (wid * 64) * 16);
  };

  f32x4 acc[8][3] = {};
  bf16x8 bb[3][2];

#define GPH(Q, BUF, STMTS, DOVM) do {                                          \
    bf16x8 ar[2][2];                                                           \
    _Pragma("unroll") for (int f = 0; f < 2; ++f)                              \
      _Pragma("unroll") for (int ks = 0; ks < 2; ++ks) {                       \
        int rw = (2 * (Q) + f) * 16 + l16;                                     \
        ar[f][ks] = *(const bf16x8*)(As[BUF][wr] + rw * 64 +                   \
                                     (((ks * 4 + g4) ^ (l16 & 7)) * 8));       \
      }                                                                        \
    if ((Q) == 0) {                                                            \
      _Pragma("unroll") for (int fb = 0; fb < 3; ++fb)                         \
        _Pragma("unroll") for (int ks = 0; ks < 2; ++ks) {                     \
          int rw = wc * 48 + fb * 16 + l16;                                    \
          bb[fb][ks] = *(const bf16x8*)(Bs[BUF] + rw * 64 +                    \
                                        (((ks * 4 + g4) ^ (l16 & 7)) * 8));    \
        }                                                                      \
    }                                                                          \
    STMTS;                                                                     \
    if (DOVM) VMC2();                                                          \
    BAR();                                                                     \
    __builtin_amdgcn_s_setprio(1);                                             \
    _Pragma("unroll") for (int f = 0; f < 2; ++f)                              \
      _Pragma("unroll") for (int fb = 0; fb < 3; ++fb)                         \
        _Pragma("unroll") for (int ks = 0; ks < 2; ++ks)                       \
          acc[2 * (Q) + f][fb] = __builtin_amdgcn_mfma_f32_16x16x32_bf16(      \
              ar[f][ks], bb[fb][ks], acc[2 * (Q) + f][fb], 0, 0, 0);           \
    __builtin_amdgcn_s_setprio(0);                                             \
    BAR();                                                                     \
  } while (0)

  // prologue: tile0 -> buf0 (B thirds + A halves), tile1 B -> buf1
  stageB(0, 0, 0); stageB(0, 1, 0); stageB(0, 2, 0);
  stageA(0, 0, 0); stageA(0, 1, 0);
  stageB(1, 0, 1); stageB(1, 1, 1); stageB(1, 2, 1);
  VMC0();
  BAR();

  for (int it = 0; it < 36; ++it) {
    int t0 = 2 * it;
    int tA1 = t0 + 1;                                 // buf1's tile (this iter)
    int tN0 = t0 + 2 < 72 ? t0 + 2 : 71;              // next buf0 tile (clamped)
    int tN1 = t0 + 3 < 72 ? t0 + 3 : 71;              // next buf1 tile (clamped)
    // phases 1-4: compute tile t0 from buf0
    GPH(0, 0, { stageA(1, 0, tA1); }, 0);
    GPH(1, 0, { stageA(1, 1, tA1); stageB(0, 0, tN0); }, 0);
    GPH(2, 0, { stageB(0, 1, tN0); }, 0);
    GPH(3, 0, { stageB(0, 2, tN0); }, 1);             // vmcnt(2): buf1 ready
    // phases 5-8: compute tile t0+1 from buf1
    GPH(0, 1, { stageA(0, 0, tN0); }, 0);
    GPH(1, 1, { stageA(0, 1, tN0); stageB(1, 0, tN1); }, 0);
    GPH(2, 1, { stageB(1, 1, tN1); }, 0);
    GPH(3, 1, { stageB(1, 2, tN1); }, 1);             // vmcnt(2): buf0 ready
  }
#undef GPH

  unsigned short* Cb = C + (size_t)kz * 2048 * 3072;
  #pragma unroll
  for (int fr = 0; fr < 8; ++fr) {
    int rowb = bm * 256 + wr * 128 + fr * 16 + g4 * 4;
    #pragma unroll
    for (int fb = 0; fb < 3; ++fb) {
      int col = bn * 192 + wc * 48 + fb * 16 + l16;
      #pragma unroll
      for (int rg = 0; rg < 4; ++rg)
        Cb[(size_t)(rowb + rg) * 3072 + col] = f2bf(acc[fr][fb][rg]);
    }
  }
}

// ---- 128x128 bf16 GEMM (output projection): f32 out + bias, raw barriers ----
__global__ __launch_bounds__(256) void kgemm_bt(const unsigned short* __restrict__ A,
    const unsigned short* __restrict__ W, float* __restrict__ C,
    const float* __restrict__ bias, int N, int nkPer) {
  const int bm = blockIdx.x, bn = blockIdx.y;
  const int tid = threadIdx.x;
  const int w = tid >> 6, lane = tid & 63;
  const int l16 = lane & 15, g4 = lane >> 4;
  const int wr = w >> 1, wcc = w & 1;
  __shared__ __align__(16) unsigned short As[2][128 * 32];
  __shared__ __align__(16) unsigned short Bs[2][128 * 32];
  f32x4 acc[4][4] = {};
  const int K = 1024;

  auto STAGE = [&](int buf, int kt) {
    #pragma unroll
    for (int r = 0; r < 2; ++r) {
      int chunk = r * 256 + w * 64 + lane;
      int row = chunk >> 2, col = (chunk & 3) * 8;
      int ldsoff = (r * 256 + w * 64) * 16;
      gload16(A + (size_t)(bm * 128 + row) * K + kt * 32 + col, (char*)As[buf] + ldsoff);
      gload16(W + (size_t)(bn * 128 + row) * K + kt * 32 + col, (char*)Bs[buf] + ldsoff);
    }
  };

  STAGE(0, 0);
  VMC0();
  BAR();
  int cur = 0;
  for (int kt = 0; kt < nkPer; ++kt) {
    if (kt + 1 < nkPer) STAGE(cur ^ 1, kt + 1);
    bf16x8 af[4], bfr[4];
    #pragma unroll
    for (int f = 0; f < 4; ++f)
      af[f] = *(const bf16x8*)(As[cur] + (wr * 64 + f * 16 + l16) * 32 + g4 * 8);
    #pragma unroll
    for (int f = 0; f < 4; ++f)
      bfr[f] = *(const bf16x8*)(Bs[cur] + (wcc * 64 + f * 16 + l16) * 32 + g4 * 8);
    __builtin_amdgcn_s_setprio(1);
    #pragma unroll
    for (int fr = 0; fr < 4; ++fr)
      #pragma unroll
      for (int fc = 0; fc < 4; ++fc)
        acc[fr][fc] = __builtin_amdgcn_mfma_f32_16x16x32_bf16(af[fr], bfr[fc], acc[fr][fc], 0, 0, 0);
    __builtin_amdgcn_s_setprio(0);
    VMC0();
    BAR();
    cur ^= 1;
  }
  #pragma unroll
  for (int fr = 0; fr < 4; ++fr) {
    int rowb = bm * 128 + wr * 64 + fr * 16 + g4 * 4;
    #pragma unroll
    for (int fc = 0; fc < 4; ++fc) {
      int col = bn * 128 + wcc * 64 + fc * 16 + l16;
      float bv = bias[col];
      #pragma unroll
      for (int rg = 0; rg < 4; ++rg)
        C[(size_t)(rowb + rg) * N + col] = acc[fr][fc][rg] + bv;
    }
  }
}

// ---- RoPE on q,k (summing split-K partials) -> Qb/Kb [h][n][d]; q scaled 1/8 ----
__global__ __launch_bounds__(256) void krope_qk(const unsigned short* __restrict__ qp,
    int splits, const float* __restrict__ rc, const float* __restrict__ rs,
    unsigned short* __restrict__ Qb, unsigned short* __restrict__ Kb) {
  unsigned int t = blockIdx.x * 256 + threadIdx.x;    // < 2048*16*32
  int d = t & 31;
  int h = (t >> 5) & 15;
  int n = t >> 9;
  float qr = 0.f, qi = 0.f, kr = 0.f, ki = 0.f;
  for (int p = 0; p < splits; ++p) {
    size_t base = (size_t)p * 2048 * O3 + (size_t)n * O3 + h * 192;
    unsigned int a = *(const unsigned int*)(qp + base + 2 * d);
    unsigned int e = *(const unsigned int*)(qp + base + 64 + 2 * d);
    qr += b2f(a & 0xffffu); qi += b2f(a >> 16);
    kr += b2f(e & 0xffffu); ki += b2f(e >> 16);
  }
  float c = rc[n * 32 + d], sn = rs[n * 32 + d];
  unsigned int qpk = (unsigned int)f2bf((qr * c - qi * sn) * 0.125f)
                   | ((unsigned int)f2bf((qr * sn + qi * c) * 0.125f) << 16);
  unsigned int kpk = (unsigned int)f2bf(kr * c - ki * sn)
                   | ((unsigned int)f2bf(kr * sn + ki * c) << 16);
  *(unsigned int*)(Qb + (size_t)h * S * HD + (size_t)n * HD + 2 * d) = qpk;
  *(unsigned int*)(Kb + (size_t)h * S * HD + (size_t)n * HD + 2 * d) = kpk;
}

// ---- pack V transposed (summing split-K partials): Vt[h][d][n] bf16 ----
__global__ __launch_bounds__(256) void kpack_vt(const unsigned short* __restrict__ qp,
    int splits, unsigned short* __restrict__ Vt) {
  const int nt = blockIdx.x;   // 0..31
  const int h  = blockIdx.y;   // 0..15
  const int tid = threadIdx.x;
  __shared__ __align__(16) unsigned short T[64][72];
  const int n0 = nt * 64;
  #pragma unroll
  for (int it = 0; it < 2; ++it) {
    int idx = it * 256 + tid;          // 0..511
    int r = idx >> 3;
    int c8 = (idx & 7) * 8;
    float acc[8] = {};
    for (int p = 0; p < splits; ++p) {
      size_t base = (size_t)p * 2048 * O3 + (size_t)(n0 + r) * O3 + h * 192 + 128 + c8;
      uint4 u = *(const uint4*)(qp + base);
      const unsigned short* pu = (const unsigned short*)&u;
      #pragma unroll
      for (int j = 0; j < 8; ++j) acc[j] += b2f(pu[j]);
    }
    #pragma unroll
    for (int j = 0; j < 8; ++j) T[c8 + j][r] = f2bf(acc[j]);
  }
  __syncthreads();
  #pragma unroll
  for (int it = 0; it < 2; ++it) {
    int idx = it * 256 + tid;          // 0..511
    int dd = idx >> 3;
    int c8 = (idx & 7) * 8;
    *(uint4*)(Vt + (size_t)h * HD * S + (size_t)dd * S + n0 + c8) = *(const uint4*)&T[dd][c8];
  }
}

// ---- flash attention, no-max softmax, swizzled LDS, raw-barrier 2-phase ----
__global__ __launch_bounds__(256) void kattn(const unsigned short* __restrict__ Qb,
    const unsigned short* __restrict__ Kb, const unsigned short* __restrict__ Vt,
    unsigned short* __restrict__ ctx) {
  const int qb = blockIdx.x, h = blockIdx.y;
  const int tid = threadIdx.x, w = tid >> 6, lane = tid & 63;
  const int l16 = lane & 15, g4 = lane >> 4;
  __shared__ __align__(16) unsigned short Ks[2][64 * 64];
  __shared__ __align__(16) unsigned short Vs[2][64 * 64];
  __shared__ __align__(16) unsigned short Ps[4][16 * 64];
  const unsigned short* Qh = Qb + (size_t)h * S * HD;
  const unsigned short* Kh = Kb + (size_t)h * S * HD;
  const unsigned short* Vh = Vt + (size_t)h * HD * S;
  bf16x8 qf[2];
  #pragma unroll
  for (int ks = 0; ks < 2; ++ks)
    qf[ks] = *(const bf16x8*)(Qh + (size_t)(qb * 64 + w * 16 + l16) * HD + ks * 32 + g4 * 8);
  f32x4 o[4] = {};
  float lp[4] = {0.f, 0.f, 0.f, 0.f};

  auto STAGE = [&](int buf, int t) {
    int kv0 = t * 64;
    #pragma unroll
    for (int r = 0; r < 2; ++r) {
      int chunk = r * 256 + w * 64 + lane;
      int row = chunk >> 3;
      int c8 = ((chunk ^ row) & 7) * 8;            // pre-swizzled global source
      int ldsoff = (r * 256 + w * 64) * 16;        // wave-uniform; HW adds lane*16
      gload16(Kh + (size_t)(kv0 + row) * HD + c8, (char*)Ks[buf] + ldsoff);
      gload16(Vh + (size_t)row * S + kv0 + c8, (char*)Vs[buf] + ldsoff);
    }
  };

  STAGE(0, 0);
  VMC0();
  BAR();
  int cur = 0;
  for (int t = 0; t < S / 64; ++t) {
    if (t + 1 < S / 64) STAGE(cur ^ 1, t + 1);     // loads fly during QK+SM+PV
    const unsigned short* Kc = Ks[cur];
    const unsigned short* Vc = Vs[cur];
    f32x4 s[4] = {};
    __builtin_amdgcn_s_setprio(1);
    #pragma unroll
    for (int fc = 0; fc < 4; ++fc) {
      int rw = fc * 16 + l16;
      #pragma unroll
      for (int ks = 0; ks < 2; ++ks) {
        bf16x8 bk = *(const bf16x8*)(Kc + rw * 64 + (((ks * 4 + g4) ^ (l16 & 7)) * 8));
        s[fc] = __builtin_amdgcn_mfma_f32_16x16x32_bf16(qf[ks], bk, s[fc], 0, 0, 0);
      }
    }
    __builtin_amdgcn_s_setprio(0);
    #pragma unroll
    for (int fc = 0; fc < 4; ++fc)
      #pragma unroll
      for (int rg = 0; rg < 4; ++rg) {
        float p = fexp(s[fc][rg]);
        lp[rg] += p;
        int row = g4 * 4 + rg;
        Ps[w][row * 64 + ((fc * 2 + (l16 >> 3)) ^ (row & 7)) * 8 + (l16 & 7)] = f2bf(p);
      }
    __builtin_amdgcn_s_setprio(1);
    #pragma unroll
    for (int ks = 0; ks < 2; ++ks) {
      bf16x8 ap = *(const bf16x8*)(Ps[w] + l16 * 64 + (((ks * 4 + g4) ^ (l16 & 7)) * 8));
      #pragma unroll
      for (int fc = 0; fc < 4; ++fc) {
        int rw = fc * 16 + l16;
        bf16x8 bv = *(const bf16x8*)(Vc + rw * 64 + (((ks * 4 + g4) ^ (l16 & 7)) * 8));
        o[fc] = __builtin_amdgcn_mfma_f32_16x16x32_bf16(ap, bv, o[fc], 0, 0, 0);
      }
    }
    __builtin_amdgcn_s_setprio(0);
    VMC0();                                        // next-tile loads landed
    BAR();                                         // single barrier per tile
    cur ^= 1;
  }
  #pragma unroll
  for (int rg = 0; rg < 4; ++rg) {
    float l = lp[rg];
    l += __shfl_xor(l, 1, 64);
    l += __shfl_xor(l, 2, 64);
    l += __shfl_xor(l, 4, 64);
    l += __shfl_xor(l, 8, 64);
    float inv = 1.f / l;
    int row = qb * 64 + w * 16 + g4 * 4 + rg;
    #pragma unroll
    for (int fc = 0; fc < 4; ++fc)
      ctx[(size_t)row * HID + h * HD + fc * 16 + l16] = f2bf(o[fc][rg] * inv);
  }
}

extern "C" void kernel_launch(void* const* d_in, const int* in_sizes, int n_in,
                              void* d_out, int out_size, void* d_ws, size_t ws_size,
                              hipStream_t stream) {
  const float* x    = (const float*)d_in[0];
  const float* bw   = (const float*)d_in[1];
  const float* sw   = (const float*)d_in[2];
  const float* sc   = (const float*)d_in[3];
  const float* ow   = (const float*)d_in[4];
  const float* ob   = (const float*)d_in[5];
  const float* grid = (const float*)d_in[6];
  const float* rc   = (const float*)d_in[7];
  const float* rs   = (const float*)d_in[8];
  float* out = (float*)d_out;
  char* ws = (char*)d_ws;

  const int splits = 2;

  unsigned short* F    = (unsigned short*)(ws);                 // 37,748,736 B
  unsigned short* Wc   = (unsigned short*)(ws + 37748736);      // 56,623,104 B
  unsigned short* Wo   = (unsigned short*)(ws + 94371840);      //  2,097,152 B
  unsigned short* qkvp = (unsigned short*)(ws + 96468992);      // 2 x 12,582,912 B
  char* tail = ws + 96468992 + (size_t)splits * 12582912;
  unsigned short* Qb   = (unsigned short*)(tail);               //  4,194,304 B
  unsigned short* Kb   = (unsigned short*)(tail + 4194304);     //  4,194,304 B
  unsigned short* Vt   = (unsigned short*)(tail + 8388608);     //  4,194,304 B
  unsigned short* ctx  = (unsigned short*)(tail + 12582912);    //  4,194,304 B

  kconv_w   <<<dim3(13824), dim3(256), 0, stream>>>(bw, sw, sc, Wc);
  kconv_outw<<<dim3(512),   dim3(256), 0, stream>>>(ow, Wo);
  kfeatures <<<dim3(8192),  dim3(256), 0, stream>>>(x, grid, F);
  kgemm256  <<<dim3(8, 16, 2), dim3(512), 0, stream>>>(F, Wc, qkvp);
  krope_qk  <<<dim3(4096),  dim3(256), 0, stream>>>(qkvp, splits, rc, rs, Qb, Kb);
  kpack_vt  <<<dim3(32, 16), dim3(256), 0, stream>>>(qkvp, splits, Vt);
  kattn     <<<dim3(32, 16), dim3(256), 0, stream>>>(Qb, Kb, Vt, ctx);
  kgemm_bt  <<<dim3(16, 8),  dim3(256), 0, stream>>>(ctx, Wo, out, ob, 1024, 32);
}

// Round 6
// 420.203 us; speedup vs baseline: 1.0033x; 1.0033x over previous
//
#include <hip/hip_runtime.h>

#define DEVI __device__ __forceinline__

typedef float f32x4 __attribute__((ext_vector_type(4)));
typedef __bf16 bf16x8 __attribute__((ext_vector_type(8)));

constexpr int S   = 2048;
constexpr int HID = 1024;
constexpr int HD  = 64;
constexpr int O3  = 3072;
constexpr int KF  = 9216;   // 1024 silu + 1024*8 spline

DEVI unsigned short f2bf(float f) {
  unsigned int u = __float_as_uint(f);
  u = (u + 0x7FFFu + ((u >> 16) & 1u)) >> 16;
  return (unsigned short)u;
}
DEVI float b2f(unsigned int u) { return __uint_as_float(u << 16); }
DEVI float fexp(float x) { return __builtin_amdgcn_exp2f(x * 1.44269504089f); }

DEVI void gload16(const void* g, void* l) {
  __builtin_amdgcn_global_load_lds((const __attribute__((address_space(1))) void*)g,
                                   (__attribute__((address_space(3))) void*)l, 16, 0, 0);
}

#define BAR() asm volatile("s_barrier" ::: "memory")
#define VMC0() asm volatile("s_waitcnt vmcnt(0)" ::: "memory")
#define VMC7() asm volatile("s_waitcnt vmcnt(7)" ::: "memory")

// ---- build bf16 combined weight Wc[3072][9216] = [base | spline*scaler] ----
__global__ __launch_bounds__(256) void kconv_w(const float* __restrict__ bw,
    const float* __restrict__ sw, const float* __restrict__ sc,
    unsigned short* __restrict__ Wc) {
  unsigned int t = blockIdx.x * 256 + threadIdx.x;    // < 3072*1152
  unsigned int o = t / 1152, jc = t % 1152;
  unsigned int j = jc * 8;
  float v[8];
  if (j < 1024) {
    const float4* p = (const float4*)(bw + (size_t)o * 1024 + j);
    float4 a = p[0], b = p[1];
    v[0]=a.x; v[1]=a.y; v[2]=a.z; v[3]=a.w; v[4]=b.x; v[5]=b.y; v[6]=b.z; v[7]=b.w;
  } else {
    unsigned int i = (j - 1024) >> 3;
    float s = sc[(size_t)o * 1024 + i];
    const float4* p = (const float4*)(sw + ((size_t)o * 1024 + i) * 8);
    float4 a = p[0], b = p[1];
    v[0]=a.x*s; v[1]=a.y*s; v[2]=a.z*s; v[3]=a.w*s; v[4]=b.x*s; v[5]=b.y*s; v[6]=b.z*s; v[7]=b.w*s;
  }
  union { unsigned short u[8]; uint4 q; } pk;
  #pragma unroll
  for (int c = 0; c < 8; ++c) pk.u[c] = f2bf(v[c]);
  *(uint4*)(Wc + (size_t)o * KF + j) = pk.q;
}

__global__ __launch_bounds__(256) void kconv_outw(const float* __restrict__ ow,
    unsigned short* __restrict__ Wo) {
  unsigned int t = blockIdx.x * 256 + threadIdx.x;    // < 131072
  unsigned int o = t >> 7, j = (t & 127) * 8;
  const float4* p = (const float4*)(ow + (size_t)o * 1024 + j);
  float4 a = p[0], b = p[1];
  float v[8] = {a.x, a.y, a.z, a.w, b.x, b.y, b.z, b.w};
  union { unsigned short u[8]; uint4 q; } pk;
  #pragma unroll
  for (int c = 0; c < 8; ++c) pk.u[c] = f2bf(v[c]);
  *(uint4*)(Wo + (size_t)o * 1024 + j) = pk.q;
}

// ---- features F[2048][9216] bf16 : [silu(x) | b_splines(x)] ----
__global__ __launch_bounds__(256) void kfeatures(const float* __restrict__ x,
    const float* __restrict__ grid, unsigned short* __restrict__ F) {
  unsigned int t = blockIdx.x * 256 + threadIdx.x;    // < 2048*1024
  unsigned int n = t >> 10, i = t & 1023;
  float xv = x[t];
  float sil = xv / (1.f + expf(-xv));
  F[(size_t)n * KF + i] = f2bf(sil);
  float g[12];
  #pragma unroll
  for (int j = 0; j < 12; ++j) g[j] = grid[j];        // wave-uniform row 0
  float b[11];
  #pragma unroll
  for (int j = 0; j < 11; ++j) b[j] = (xv >= g[j] && xv < g[j + 1]) ? 1.f : 0.f;
  #pragma unroll
  for (int ord = 1; ord <= 3; ++ord) {
    float inv[11];
    #pragma unroll
    for (int a = 0; a + ord < 12 && a < 11; ++a) {
      float d = g[a + ord] - g[a];
      float r = __builtin_amdgcn_rcpf(d);
      inv[a] = r * (2.f - d * r);                     // one Newton step
    }
    #pragma unroll
    for (int j = 0; j + ord < 11; ++j)
      b[j] = (xv - g[j]) * inv[j] * b[j]
           + (g[j + ord + 1] - xv) * inv[j + 1] * b[j + 1];
  }
  union { unsigned short u[8]; uint4 q; } pk;
  #pragma unroll
  for (int c = 0; c < 8; ++c) pk.u[c] = f2bf(b[c]);
  *(uint4*)(F + (size_t)n * KF + 1024 + i * 8) = pk.q;
}

// ---- 8-phase 256x192 bf16 GEMM, deep pipeline: A triple-buffered (staged a
// full iteration ahead), B even/odd double-buffered, symmetric vmcnt(7) at
// ph4/ph8 (the 7 newest outstanding loads are exactly the not-yet-needed
// ones; every waited-for load was issued >=5 phases earlier).
// grid (8,16,2) = 256 blocks = 1/CU.  512 threads, 8 waves (2Mx4N),
// per-wave 128x48 out.  LDS 144KB.
__global__ __launch_bounds__(512) void kgemm256(const unsigned short* __restrict__ A,
    const unsigned short* __restrict__ W, unsigned short* __restrict__ C) {
  int lin = blockIdx.x + (blockIdx.y << 3) + (blockIdx.z << 7);
  int swz = (lin & 7) * 32 + (lin >> 3);              // bijective XCD swizzle
  int kz = swz >> 7;
  int r = swz & 127;
  int bm = r >> 4, bn = r & 15;
  const int tid = threadIdx.x;
  const int wid = tid >> 6;
  const int lane = tid & 63;
  const int l16 = lane & 15, g4 = lane >> 4;
  const int wr = wid >> 2, wc = wid & 3;
  const int koff = kz * 72;                           // K-tiles of 64

  __shared__ __align__(16) unsigned short As[3][256 * 64];   // 3 x 32 KB
  __shared__ __align__(16) unsigned short Bs[2][192 * 64];   // 2 x 24 KB

  const size_t rA0 = (size_t)bm * 256;
  const size_t rB0 = (size_t)bn * 192;

  auto stageA = [&](int buf, int half, int t) {       // 128x64 half, 2 loads/wave
    if (t > 71) t = 71;
    const unsigned short* src = A + (rA0 + half * 128) * (size_t)KF + (size_t)(koff + t) * 64;
    char* lds = (char*)&As[buf][0] + half * 16384;
    #pragma unroll
    for (int rr = 0; rr < 2; ++rr) {
      int chunk = rr * 512 + tid;
      int row = chunk >> 3;
      int c8 = (chunk & 7) ^ (row & 7);               // pre-swizzled source
      gload16(src + (size_t)row * KF + c8 * 8, lds + (rr * 512 + wid * 64) * 16);
    }
  };
  auto stageB = [&](int buf, int third, int t) {      // 64x64 third, 1 load/wave
    if (t > 71) t = 71;
    const unsigned short* src = W + (rB0 + third * 64) * (size_t)KF + (size_t)(koff + t) * 64;
    char* lds = (char*)&Bs[buf][0] + third * 8192;
    int row = tid >> 3;
    int c8 = (tid & 7) ^ (row & 7);
    gload16(src + (size_t)row * KF + c8 * 8, lds + (wid * 64) * 16);
  };

  f32x4 acc[8][3] = {};
  bf16x8 bb[3][2];

#define GPH(Q, ABUF, BBUF, STMTS, DOVM) do {                                   \
    bf16x8 ar[2][2];                                                           \
    _Pragma("unroll") for (int f = 0; f < 2; ++f)                              \
      _Pragma("unroll") for (int ks = 0; ks < 2; ++ks) {                       \
        int rw = wr * 128 + (2 * (Q) + f) * 16 + l16;                          \
        ar[f][ks] = *(const bf16x8*)(&As[ABUF][0] + rw * 64 +                  \
                                     (((ks * 4 + g4) ^ (l16 & 7)) * 8));       \
      }                                                                        \
    if ((Q) == 0) {                                                            \
      _Pragma("unroll") for (int fb = 0; fb < 3; ++fb)                         \
        _Pragma("unroll") for (int ks = 0; ks < 2; ++ks) {                     \
          int rw = wc * 48 + fb * 16 + l16;                                    \
          bb[fb][ks] = *(const bf16x8*)(&Bs[BBUF][0] + rw * 64 +               \
                                        (((ks * 4 + g4) ^ (l16 & 7)) * 8));    \
        }                                                                      \
    }                                                                          \
    STMTS;                                                                     \
    if (DOVM) VMC7();                                                          \
    BAR();                                                                     \
    __builtin_amdgcn_s_setprio(1);                                             \
    _Pragma("unroll") for (int f = 0; f < 2; ++f)                              \
      _Pragma("unroll") for (int fb = 0; fb < 3; ++fb)                         \
        _Pragma("unroll") for (int ks = 0; ks < 2; ++ks)                       \
          acc[2 * (Q) + f][fb] = __builtin_amdgcn_mfma_f32_16x16x32_bf16(      \
              ar[f][ks], bb[fb][ks], acc[2 * (Q) + f][fb], 0, 0, 0);           \
    __builtin_amdgcn_s_setprio(0);                                             \
    BAR();                                                                     \
  } while (0)

  // prologue: A(0)->As[0], B(0)->Bs[0], A(1)->As[1], B(1)->Bs[1]
  stageA(0, 0, 0); stageA(0, 1, 0);
  stageB(0, 0, 0); stageB(0, 1, 0); stageB(0, 2, 0);
  stageA(1, 0, 1); stageA(1, 1, 1);
  stageB(1, 0, 1); stageB(1, 1, 1); stageB(1, 2, 1);
  VMC0();
  BAR();

  int a0 = 0, a1 = 1, a2 = 2;
  #pragma unroll 3
  for (int it = 0; it < 36; ++it) {
    int t0 = 2 * it;
    // phases 1-4: tile t0 from As[a0], Bs[0]; stage A(t0+2)->a2, B(t0+2)->Bs0
    GPH(0, a0, 0, { stageA(a2, 0, t0 + 2); }, 0);
    GPH(1, a0, 0, { stageA(a2, 1, t0 + 2); stageB(0, 0, t0 + 2); }, 0);
    GPH(2, a0, 0, { stageB(0, 1, t0 + 2); }, 0);
    GPH(3, a0, 0, { stageB(0, 2, t0 + 2); }, 1);   // vmcnt(7): buf a1 + Bs1 ready
    // phases 5-8: tile t0+1 from As[a1], Bs[1]; stage A(t0+3)->a0, B(t0+3)->Bs1
    GPH(0, a1, 1, { stageA(a0, 0, t0 + 3); }, 0);
    GPH(1, a1, 1, { stageA(a0, 1, t0 + 3); stageB(1, 0, t0 + 3); }, 0);
    GPH(2, a1, 1, { stageB(1, 1, t0 + 3); }, 0);
    GPH(3, a1, 1, { stageB(1, 2, t0 + 3); }, 1);   // vmcnt(7): a2 + Bs0 ready
    int tmp = a0; a0 = a2; a2 = a1; a1 = tmp;       // (a0,a1,a2) <- (a2,a0,a1)
  }
#undef GPH
  VMC0();

  unsigned short* Cb = C + (size_t)kz * 2048 * 3072;
  #pragma unroll
  for (int fr = 0; fr < 8; ++fr) {
    int rowb = bm * 256 + wr * 128 + fr * 16 + g4 * 4;
    #pragma unroll
    for (int fb = 0; fb < 3; ++fb) {
      int col = bn * 192 + wc * 48 + fb * 16 + l16;
      #pragma unroll
      for (int rg = 0; rg < 4; ++rg)
        Cb[(size_t)(rowb + rg) * 3072 + col] = f2bf(acc[fr][fb][rg]);
    }
  }
}

// ---- 128x128 bf16 GEMM (output projection): f32 out + bias, raw barriers ----
__global__ __launch_bounds__(256) void kgemm_bt(const unsigned short* __restrict__ A,
    const unsigned short* __restrict__ W, float* __restrict__ C,
    const float* __restrict__ bias, int N, int nkPer) {
  const int bm = blockIdx.x, bn = blockIdx.y;
  const int tid = threadIdx.x;
  const int w = tid >> 6, lane = tid & 63;
  const int l16 = lane & 15, g4 = lane >> 4;
  const int wr = w >> 1, wcc = w & 1;
  __shared__ __align__(16) unsigned short As[2][128 * 32];
  __shared__ __align__(16) unsigned short Bs[2][128 * 32];
  f32x4 acc[4][4] = {};
  const int K = 1024;

  auto STAGE = [&](int buf, int kt) {
    #pragma unroll
    for (int r = 0; r < 2; ++r) {
      int chunk = r * 256 + w * 64 + lane;
      int row = chunk >> 2, col = (chunk & 3) * 8;
      int ldsoff = (r * 256 + w * 64) * 16;
      gload16(A + (size_t)(bm * 128 + row) * K + kt * 32 + col, (char*)As[buf] + ldsoff);
      gload16(W + (size_t)(bn * 128 + row) * K + kt * 32 + col, (char*)Bs[buf] + ldsoff);
    }
  };

  STAGE(0, 0);
  VMC0();
  BAR();
  int cur = 0;
  for (int kt = 0; kt < nkPer; ++kt) {
    if (kt + 1 < nkPer) STAGE(cur ^ 1, kt + 1);
    bf16x8 af[4], bfr[4];
    #pragma unroll
    for (int f = 0; f < 4; ++f)
      af[f] = *(const bf16x8*)(As[cur] + (wr * 64 + f * 16 + l16) * 32 + g4 * 8);
    #pragma unroll
    for (int f = 0; f < 4; ++f)
      bfr[f] = *(const bf16x8*)(Bs[cur] + (wcc * 64 + f * 16 + l16) * 32 + g4 * 8);
    __builtin_amdgcn_s_setprio(1);
    #pragma unroll
    for (int fr = 0; fr < 4; ++fr)
      #pragma unroll
      for (int fc = 0; fc < 4; ++fc)
        acc[fr][fc] = __builtin_amdgcn_mfma_f32_16x16x32_bf16(af[fr], bfr[fc], acc[fr][fc], 0, 0, 0);
    __builtin_amdgcn_s_setprio(0);
    VMC0();
    BAR();
    cur ^= 1;
  }
  #pragma unroll
  for (int fr = 0; fr < 4; ++fr) {
    int rowb = bm * 128 + wr * 64 + fr * 16 + g4 * 4;
    #pragma unroll
    for (int fc = 0; fc < 4; ++fc) {
      int col = bn * 128 + wcc * 64 + fc * 16 + l16;
      float bv = bias[col];
      #pragma unroll
      for (int rg = 0; rg < 4; ++rg)
        C[(size_t)(rowb + rg) * N + col] = acc[fr][fc][rg] + bv;
    }
  }
}

// ---- RoPE on q,k (summing split-K partials) -> Qb/Kb [h][n][d]; q scaled 1/8 ----
__global__ __launch_bounds__(256) void krope_qk(const unsigned short* __restrict__ qp,
    int splits, const float* __restrict__ rc, const float* __restrict__ rs,
    unsigned short* __restrict__ Qb, unsigned short* __restrict__ Kb) {
  unsigned int t = blockIdx.x * 256 + threadIdx.x;    // < 2048*16*32
  int d = t & 31;
  int h = (t >> 5) & 15;
  int n = t >> 9;
  float qr = 0.f, qi = 0.f, kr = 0.f, ki = 0.f;
  for (int p = 0; p < splits; ++p) {
    size_t base = (size_t)p * 2048 * O3 + (size_t)n * O3 + h * 192;
    unsigned int a = *(const unsigned int*)(qp + base + 2 * d);
    unsigned int e = *(const unsigned int*)(qp + base + 64 + 2 * d);
    qr += b2f(a & 0xffffu); qi += b2f(a >> 16);
    kr += b2f(e & 0xffffu); ki += b2f(e >> 16);
  }
  float c = rc[n * 32 + d], sn = rs[n * 32 + d];
  unsigned int qpk = (unsigned int)f2bf((qr * c - qi * sn) * 0.125f)
                   | ((unsigned int)f2bf((qr * sn + qi * c) * 0.125f) << 16);
  unsigned int kpk = (unsigned int)f2bf(kr * c - ki * sn)
                   | ((unsigned int)f2bf(kr * sn + ki * c) << 16);
  *(unsigned int*)(Qb + (size_t)h * S * HD + (size_t)n * HD + 2 * d) = qpk;
  *(unsigned int*)(Kb + (size_t)h * S * HD + (size_t)n * HD + 2 * d) = kpk;
}

// ---- pack V transposed (summing split-K partials): Vt[h][d][n] bf16 ----
__global__ __launch_bounds__(256) void kpack_vt(const unsigned short* __restrict__ qp,
    int splits, unsigned short* __restrict__ Vt) {
  const int nt = blockIdx.x;   // 0..31
  const int h  = blockIdx.y;   // 0..15
  const int tid = threadIdx.x;
  __shared__ __align__(16) unsigned short T[64][72];
  const int n0 = nt * 64;
  #pragma unroll
  for (int it = 0; it < 2; ++it) {
    int idx = it * 256 + tid;          // 0..511
    int r = idx >> 3;
    int c8 = (idx & 7) * 8;
    float acc[8] = {};
    for (int p = 0; p < splits; ++p) {
      size_t base = (size_t)p * 2048 * O3 + (size_t)(n0 + r) * O3 + h * 192 + 128 + c8;
      uint4 u = *(const uint4*)(qp + base);
      const unsigned short* pu = (const unsigned short*)&u;
      #pragma unroll
      for (int j = 0; j < 8; ++j) acc[j] += b2f(pu[j]);
    }
    #pragma unroll
    for (int j = 0; j < 8; ++j) T[c8 + j][r] = f2bf(acc[j]);
  }
  __syncthreads();
  #pragma unroll
  for (int it = 0; it < 2; ++it) {
    int idx = it * 256 + tid;          // 0..511
    int dd = idx >> 3;
    int c8 = (idx & 7) * 8;
    *(uint4*)(Vt + (size_t)h * HD * S + (size_t)dd * S + n0 + c8) = *(const uint4*)&T[dd][c8];
  }
}

// ---- flash attention, no-max softmax, swizzled LDS, raw-barrier 2-phase ----
__global__ __launch_bounds__(256) void kattn(const unsigned short* __restrict__ Qb,
    const unsigned short* __restrict__ Kb, const unsigned short* __restrict__ Vt,
    unsigned short* __restrict__ ctx) {
  const int qb = blockIdx.x, h = blockIdx.y;
  const int tid = threadIdx.x, w = tid >> 6, lane = tid & 63;
  const int l16 = lane & 15, g4 = lane >> 4;
  __shared__ __align__(16) unsigned short Ks[2][64 * 64];
  __shared__ __align__(16) unsigned short Vs[2][64 * 64];
  __shared__ __align__(16) unsigned short Ps[4][16 * 64];
  const unsigned short* Qh = Qb + (size_t)h * S * HD;
  const unsigned short* Kh = Kb + (size_t)h * S * HD;
  const unsigned short* Vh = Vt + (size_t)h * HD * S;
  bf16x8 qf[2];
  #pragma unroll
  for (int ks = 0; ks < 2; ++ks)
    qf[ks] = *(const bf16x8*)(Qh + (size_t)(qb * 64 + w * 16 + l16) * HD + ks * 32 + g4 * 8);
  f32x4 o[4] = {};
  float lp[4] = {0.f, 0.f, 0.f, 0.f};

  auto STAGE = [&](int buf, int t) {
    int kv0 = t * 64;
    #pragma unroll
    for (int r = 0; r < 2; ++r) {
      int chunk = r * 256 + w * 64 + lane;
      int row = chunk >> 3;
      int c8 = ((chunk ^ row) & 7) * 8;            // pre-swizzled global source
      int ldsoff = (r * 256 + w * 64) * 16;        // wave-uniform; HW adds lane*16
      gload16(Kh + (size_t)(kv0 + row) * HD + c8, (char*)Ks[buf] + ldsoff);
      gload16(Vh + (size_t)row * S + kv0 + c8, (char*)Vs[buf] + ldsoff);
    }
  };

  STAGE(0, 0);
  VMC0();
  BAR();
  int cur = 0;
  for (int t = 0; t < S / 64; ++t) {
    if (t + 1 < S / 64) STAGE(cur ^ 1, t + 1);     // loads fly during QK+SM+PV
    const unsigned short* Kc = Ks[cur];
    const unsigned short* Vc = Vs[cur];
    f32x4 s[4] = {};
    __builtin_amdgcn_s_setprio(1);
    #pragma unroll
    for (int fc = 0; fc < 4; ++fc) {
      int rw = fc * 16 + l16;
      #pragma unroll
      for (int ks = 0; ks < 2; ++ks) {
        bf16x8 bk = *(const bf16x8*)(Kc + rw * 64 + (((ks * 4 + g4) ^ (l16 & 7)) * 8));
        s[fc] = __builtin_amdgcn_mfma_f32_16x16x32_bf16(qf[ks], bk, s[fc], 0, 0, 0);
      }
    }
    __builtin_amdgcn_s_setprio(0);
    #pragma unroll
    for (int fc = 0; fc < 4; ++fc)
      #pragma unroll
      for (int rg = 0; rg < 4; ++rg) {
        float p = fexp(s[fc][rg]);
        lp[rg] += p;
        int row = g4 * 4 + rg;
        Ps[w][row * 64 + ((fc * 2 + (l16 >> 3)) ^ (row & 7)) * 8 + (l16 & 7)] = f2bf(p);
      }
    __builtin_amdgcn_s_setprio(1);
    #pragma unroll
    for (int ks = 0; ks < 2; ++ks) {
      bf16x8 ap = *(const bf16x8*)(Ps[w] + l16 * 64 + (((ks * 4 + g4) ^ (l16 & 7)) * 8));
      #pragma unroll
      for (int fc = 0; fc < 4; ++fc) {
        int rw = fc * 16 + l16;
        bf16x8 bv = *(const bf16x8*)(Vc + rw * 64 + (((ks * 4 + g4) ^ (l16 & 7)) * 8));
        o[fc] = __builtin_amdgcn_mfma_f32_16x16x32_bf16(ap, bv, o[fc], 0, 0, 0);
      }
    }
    __builtin_amdgcn_s_setprio(0);
    VMC0();                                        // next-tile loads landed
    BAR();                                         // single barrier per tile
    cur ^= 1;
  }
  #pragma unroll
  for (int rg = 0; rg < 4; ++rg) {
    float l = lp[rg];
    l += __shfl_xor(l, 1, 64);
    l += __shfl_xor(l, 2, 64);
    l += __shfl_xor(l, 4, 64);
    l += __shfl_xor(l, 8, 64);
    float inv = 1.f / l;
    int row = qb * 64 + w * 16 + g4 * 4 + rg;
    #pragma unroll
    for (int fc = 0; fc < 4; ++fc)
      ctx[(size_t)row * HID + h * HD + fc * 16 + l16] = f2bf(o[fc][rg] * inv);
  }
}

extern "C" void kernel_launch(void* const* d_in, const int* in_sizes, int n_in,
                              void* d_out, int out_size, void* d_ws, size_t ws_size,
                              hipStream_t stream) {
  const float* x    = (const float*)d_in[0];
  const float* bw   = (const float*)d_in[1];
  const float* sw   = (const float*)d_in[2];
  const float* sc   = (const float*)d_in[3];
  const float* ow   = (const float*)d_in[4];
  const float* ob   = (const float*)d_in[5];
  const float* grid = (const float*)d_in[6];
  const float* rc   = (const float*)d_in[7];
  const float* rs   = (const float*)d_in[8];
  float* out = (float*)d_out;
  char* ws = (char*)d_ws;

  const int splits = 2;

  unsigned short* F    = (unsigned short*)(ws);                 // 37,748,736 B
  unsigned short* Wc   = (unsigned short*)(ws + 37748736);      // 56,623,104 B
  unsigned short* Wo   = (unsigned short*)(ws + 94371840);      //  2,097,152 B
  unsigned short* qkvp = (unsigned short*)(ws + 96468992);      // 2 x 12,582,912 B
  char* tail = ws + 96468992 + (size_t)splits * 12582912;
  unsigned short* Qb   = (unsigned short*)(tail);               //  4,194,304 B
  unsigned short* Kb   = (unsigned short*)(tail + 4194304);     //  4,194,304 B
  unsigned short* Vt   = (unsigned short*)(tail + 8388608);     //  4,194,304 B
  unsigned short* ctx  = (unsigned short*)(tail + 12582912);    //  4,194,304 B

  kconv_w   <<<dim3(13824), dim3(256), 0, stream>>>(bw, sw, sc, Wc);
  kconv_outw<<<dim3(512),   dim3(256), 0, stream>>>(ow, Wo);
  kfeatures <<<dim3(8192),  dim3(256), 0, stream>>>(x, grid, F);
  kgemm256  <<<dim3(8, 16, 2), dim3(512), 0, stream>>>(F, Wc, qkvp);
  krope_qk  <<<dim3(4096),  dim3(256), 0, stream>>>(qkvp, splits, rc, rs, Qb, Kb);
  kpack_vt  <<<dim3(32, 16), dim3(256), 0, stream>>>(qkvp, splits, Vt);
  kattn     <<<dim3(32, 16), dim3(256), 0, stream>>>(Qb, Kb, Vt, ctx);
  kgemm_bt  <<<dim3(16, 8),  dim3(256), 0, stream>>>(ctx, Wo, out, ob, 1024, 32);
}